// Round 3
// baseline (1152.605 us; speedup 1.0000x reference)
//
#include <hip/hip_runtime.h>
#include <hip/hip_bf16.h>

#define BB 64
#define SS 200
#define DD 1024
#define HH 16
#define HD 64
#define N3 3072
#define MM (BB*SS)       // 12800
#define KK DD            // 1024

using half8 = __attribute__((ext_vector_type(8))) _Float16;
using f32x4 = __attribute__((ext_vector_type(4))) float;

__device__ __forceinline__ void gload16(const void* g, void* l) {
    __builtin_amdgcn_global_load_lds(
        (const __attribute__((address_space(1))) void*)g,
        (__attribute__((address_space(3))) void*)l, 16, 0, 0);
}

// ---------------- fp32 -> fp16 conversion (grid-stride, 8 elems/thread/iter) ----------------
__global__ __launch_bounds__(256) void f32_to_f16_kernel(const float* __restrict__ in,
                                                         _Float16* __restrict__ out, int n8) {
    int i = blockIdx.x * 256 + threadIdx.x;
    int stride = gridDim.x * 256;
    for (; i < n8; i += stride) {
        float4 a = ((const float4*)in)[i * 2];
        float4 b = ((const float4*)in)[i * 2 + 1];
        half8 h;
        h[0] = (_Float16)a.x; h[1] = (_Float16)a.y; h[2] = (_Float16)a.z; h[3] = (_Float16)a.w;
        h[4] = (_Float16)b.x; h[5] = (_Float16)b.y; h[6] = (_Float16)b.z; h[7] = (_Float16)b.w;
        ((half8*)out)[i] = h;
    }
}

// ---------------- RoPE cos/sin table: [S][32] pairs (cos, sin) ----------------
__global__ __launch_bounds__(256) void rope_table_kernel(float* __restrict__ rope) {
    int t = blockIdx.x * 256 + threadIdx.x;
    if (t >= SS * 32) return;
    int s = t >> 5, i = t & 31;
    float inv = powf(10000.0f, -(float)(2 * i) / 64.0f);
    float ang = (float)s * inv;
    rope[t * 2 + 0] = cosf(ang);
    rope[t * 2 + 1] = sinf(ang);
}

// ---------------- QKV GEMM: fp16 MFMA 16x16x32, 128x128 tile, BK=32 ----------------
// C[m][n] = sum_k x[m][k]*W[n][k]; epilogue: +bias, RoPE(q,k), scatter [B][H][S][hd] fp32
__global__ __launch_bounds__(256) void qkv_gemm_f16_kernel(
    const _Float16* __restrict__ Xh, const _Float16* __restrict__ Wh,
    const float* __restrict__ bias, const float* __restrict__ rope,
    float* __restrict__ qo, float* __restrict__ ko, float* __restrict__ vo)
{
    __shared__ _Float16 As[128 * 32];
    __shared__ _Float16 Bs[128 * 32];

    const int t = threadIdx.x;
    const int w = t >> 6, lane = t & 63;
    const int wm = w >> 1, wn = w & 1;
    const int m0 = blockIdx.y * 128, n0 = blockIdx.x * 128;

    f32x4 acc[4][4];
    #pragma unroll
    for (int i = 0; i < 4; ++i)
        #pragma unroll
        for (int j = 0; j < 4; ++j) acc[i][j] = (f32x4)0.f;

    // precompute per-thread staging coords (2 chunks per tile)
    // slot = c*256 + t; row r = slot>>2; sl = slot&3; global k-slot = sl ^ ((r>>1)&3)
    int srow[2], scol[2], sdst[2];
    #pragma unroll
    for (int c = 0; c < 2; ++c) {
        int slot = c * 256 + t;
        int r = slot >> 2, sl = slot & 3;
        srow[c] = r;
        scol[c] = (sl ^ ((r >> 1) & 3)) << 3;        // fp16 element offset within 32-col row
        sdst[c] = (c * 256 + w * 64) * 8;            // wave-uniform LDS base (halves)
    }
    // frag read coords
    const int arow = wm * 64 + (lane & 15);          // +mi*16
    const int brow = wn * 64 + (lane & 15);          // +ni*16
    const int kq = lane >> 4;                        // desired k-slot 0..3

    for (int kt = 0; kt < KK; kt += 32) {
        __syncthreads();
        #pragma unroll
        for (int c = 0; c < 2; ++c) {
            gload16(Xh + (size_t)(m0 + srow[c]) * KK + kt + scol[c], &As[sdst[c]]);
            gload16(Wh + (size_t)(n0 + srow[c]) * KK + kt + scol[c], &Bs[sdst[c]]);
        }
        __syncthreads();

        half8 af[4], bf[4];
        #pragma unroll
        for (int mi = 0; mi < 4; ++mi) {
            int r = arow + mi * 16;
            af[mi] = *(const half8*)&As[r * 32 + ((kq ^ ((r >> 1) & 3)) << 3)];
        }
        #pragma unroll
        for (int ni = 0; ni < 4; ++ni) {
            int r = brow + ni * 16;
            bf[ni] = *(const half8*)&Bs[r * 32 + ((kq ^ ((r >> 1) & 3)) << 3)];
        }
        #pragma unroll
        for (int mi = 0; mi < 4; ++mi)
            #pragma unroll
            for (int ni = 0; ni < 4; ++ni)
                acc[mi][ni] = __builtin_amdgcn_mfma_f32_16x16x32_f16(af[mi], bf[ni], acc[mi][ni], 0, 0, 0);
    }

    // ---- epilogue: bias + RoPE + scatter ----
    #pragma unroll
    for (int ni = 0; ni < 4; ++ni) {
        int n = n0 + wn * 64 + ni * 16 + (lane & 15);
        float bv = bias[n];
        int h = n / 192;
        int rr = n - h * 192;
        int which = rr >> 6;          // 0=q 1=k 2=v (uniform per fragment)
        int j = rr & 63;
        int jp = j >> 1;
        float* dst = (which == 0) ? qo : ((which == 1) ? ko : vo);
        #pragma unroll
        for (int mi = 0; mi < 4; ++mi) {
            #pragma unroll
            for (int reg = 0; reg < 4; ++reg) {
                int m = m0 + wm * 64 + mi * 16 + (lane >> 4) * 4 + reg;
                int b_ = m / SS, s_ = m - b_ * SS;
                float v = acc[mi][ni][reg] + bv;
                float p = __shfl_xor(v, 1);
                float o;
                if (which < 2) {
                    float2 cs = *(const float2*)&rope[(s_ * 32 + jp) * 2];
                    o = (j & 1) ? fmaf(p, cs.y, v * cs.x) : fmaf(v, cs.x, -p * cs.y);
                } else {
                    o = v;
                }
                dst[(((size_t)b_ * HH + h) * SS + s_) * HD + j] = o;
            }
        }
    }
}

// ---------------- Attention: one block per (b,h), K^T + V staged in LDS (fp32 VALU) ----------------
__global__ __launch_bounds__(256) void attn_kernel(
    const float* __restrict__ q, const float* __restrict__ k,
    const float* __restrict__ v, float* __restrict__ out)
{
    __shared__ float KT[64][201];
    __shared__ float Vs[SS * 64];
    __shared__ float Pbuf[4][SS];
    __shared__ float qbuf[4][64];

    const int bh = blockIdx.x;
    const int b_ = bh >> 4, h = bh & 15;
    const int tid = threadIdx.x;
    const int w = tid >> 6, lane = tid & 63;

    const float* kbase = k + (size_t)bh * SS * HD;
    const float* vbase = v + (size_t)bh * SS * HD;

    for (int idx = tid; idx < SS * 16; idx += 256) {
        int key = idx >> 4, dp = idx & 15;
        float4 kv = *(const float4*)(kbase + key * 64 + dp * 4);
        KT[dp * 4 + 0][key] = kv.x;
        KT[dp * 4 + 1][key] = kv.y;
        KT[dp * 4 + 2][key] = kv.z;
        KT[dp * 4 + 3][key] = kv.w;
    }
    for (int idx = tid; idx < SS * 16; idx += 256) {
        *(float4*)&Vs[idx * 4] = *((const float4*)vbase + idx);
    }
    __syncthreads();

    const float* qrow = q + (size_t)bh * SS * HD;
    // per-wave private buffers; intra-wave LDS RAW ordered by lgkmcnt -> no barriers in loop
    for (int s_ = w; s_ < SS; s_ += 4) {
        float qv = qrow[s_ * 64 + lane] * 0.125f;
        qbuf[w][lane] = qv;

        float lmax = -3.0e38f;
        for (int kk = lane; kk <= s_; kk += 64) {
            float sc = 0.f;
            #pragma unroll
            for (int d = 0; d < 64; d += 2) {
                float2 qd = *(const float2*)&qbuf[w][d];
                sc = fmaf(qd.x, KT[d][kk], sc);
                sc = fmaf(qd.y, KT[d + 1][kk], sc);
            }
            Pbuf[w][kk] = sc;
            lmax = fmaxf(lmax, sc);
        }

        #pragma unroll
        for (int off = 32; off > 0; off >>= 1)
            lmax = fmaxf(lmax, __shfl_xor(lmax, off));

        float lsum = 0.f;
        for (int kk = lane; kk <= s_; kk += 64) {
            float p = __expf(Pbuf[w][kk] - lmax);
            Pbuf[w][kk] = p;
            lsum += p;
        }

        #pragma unroll
        for (int off = 32; off > 0; off >>= 1)
            lsum += __shfl_xor(lsum, off);

        float o = 0.f;
        int nk = s_ + 1;
        int k2 = nk & ~1;
        for (int kk = 0; kk < k2; kk += 2) {
            float2 p2 = *(const float2*)&Pbuf[w][kk];
            o = fmaf(p2.x, Vs[kk * 64 + lane], o);
            o = fmaf(p2.y, Vs[kk * 64 + 64 + lane], o);
        }
        if (k2 < nk) o = fmaf(Pbuf[w][k2], Vs[k2 * 64 + lane], o);

        out[((size_t)(b_ * SS + s_)) * DD + h * 64 + lane] = o / lsum;
    }
}

extern "C" void kernel_launch(void* const* d_in, const int* in_sizes, int n_in,
                              void* d_out, int out_size, void* d_ws, size_t ws_size,
                              hipStream_t stream) {
    const float* x    = (const float*)d_in[0];
    // d_in[1] = mask: deterministic causal tril -> applied analytically
    const float* W    = (const float*)d_in[2];
    const float* bias = (const float*)d_in[3];
    float* out = (float*)d_out;

    char* ws = (char*)d_ws;
    float*    rope = (float*)ws;                                  // 51.2 KB
    _Float16* Xh   = (_Float16*)(ws + 65536);                     // 26.2 MB
    _Float16* Wh   = (_Float16*)(ws + 65536 + (size_t)MM * KK * 2);          // 6.3 MB
    float*    q    = (float*)(ws + 65536 + (size_t)(MM + N3) * KK * 2);      // 52.4 MB each
    float*    kp   = q + (size_t)BB * HH * SS * HD;
    float*    vp   = kp + (size_t)BB * HH * SS * HD;

    f32_to_f16_kernel<<<2048, 256, 0, stream>>>(x, Xh, MM * KK / 8);
    f32_to_f16_kernel<<<1024, 256, 0, stream>>>(W, Wh, N3 * KK / 8);
    rope_table_kernel<<<(SS * 32 + 255) / 256, 256, 0, stream>>>(rope);
    qkv_gemm_f16_kernel<<<dim3(N3 / 128, MM / 128), dim3(256), 0, stream>>>(Xh, Wh, bias, rope, q, kp, vp);
    attn_kernel<<<BB * HH, 256, 0, stream>>>(q, kp, vp, out);
}

// Round 4
// 359.003 us; speedup vs baseline: 3.2106x; 3.2106x over previous
//
#include <hip/hip_runtime.h>
#include <hip/hip_bf16.h>

#define BB 64
#define SS 200
#define DD 1024
#define HH 16
#define HD 64
#define N3 3072
#define MM (BB*SS)       // 12800
#define KK DD            // 1024
#define SP 208           // padded S (K_lds rows / VT cols)

using half8 = __attribute__((ext_vector_type(8))) _Float16;
using f32x4 = __attribute__((ext_vector_type(4))) float;

__device__ __forceinline__ void gload16(const void* g, void* l) {
    __builtin_amdgcn_global_load_lds(
        (const __attribute__((address_space(1))) void*)g,
        (__attribute__((address_space(3))) void*)l, 16, 0, 0);
}

// ---------------- fp32 -> fp16 conversion ----------------
__global__ __launch_bounds__(256) void f32_to_f16_kernel(const float* __restrict__ in,
                                                         _Float16* __restrict__ out, int n8) {
    int i = blockIdx.x * 256 + threadIdx.x;
    int stride = gridDim.x * 256;
    for (; i < n8; i += stride) {
        float4 a = ((const float4*)in)[i * 2];
        float4 b = ((const float4*)in)[i * 2 + 1];
        half8 h;
        h[0] = (_Float16)a.x; h[1] = (_Float16)a.y; h[2] = (_Float16)a.z; h[3] = (_Float16)a.w;
        h[4] = (_Float16)b.x; h[5] = (_Float16)b.y; h[6] = (_Float16)b.z; h[7] = (_Float16)b.w;
        ((half8*)out)[i] = h;
    }
}

// ---------------- RoPE cos/sin table: [S][32] pairs (cos, sin) ----------------
__global__ __launch_bounds__(256) void rope_table_kernel(float* __restrict__ rope) {
    int t = blockIdx.x * 256 + threadIdx.x;
    if (t >= SS * 32) return;
    int s = t >> 5, i = t & 31;
    float inv = powf(10000.0f, -(float)(2 * i) / 64.0f);
    float ang = (float)s * inv;
    rope[t * 2 + 0] = cosf(ang);
    rope[t * 2 + 1] = sinf(ang);
}

// ---------------- QKV GEMM: fp16 MFMA 16x16x32, 128x128 tile, BK=32 ----------------
// Epilogue: +bias, RoPE(q,k), q scaled by 1/8; writes fp16 Q,K [bh][S][hd], fp16 V^T [bh][hd][SP]
__global__ __launch_bounds__(256) void qkv_gemm_f16_kernel(
    const _Float16* __restrict__ Xh, const _Float16* __restrict__ Wh,
    const float* __restrict__ bias, const float* __restrict__ rope,
    _Float16* __restrict__ qo, _Float16* __restrict__ ko, _Float16* __restrict__ vt)
{
    __shared__ _Float16 As[128 * 32];
    __shared__ _Float16 Bs[128 * 32];

    const int t = threadIdx.x;
    const int w = t >> 6, lane = t & 63;
    const int wm = w >> 1, wn = w & 1;
    const int m0 = blockIdx.y * 128, n0 = blockIdx.x * 128;

    f32x4 acc[4][4];
    #pragma unroll
    for (int i = 0; i < 4; ++i)
        #pragma unroll
        for (int j = 0; j < 4; ++j) acc[i][j] = (f32x4)0.f;

    int srow[2], scol[2], sdst[2];
    #pragma unroll
    for (int c = 0; c < 2; ++c) {
        int slot = c * 256 + t;
        int r = slot >> 2, sl = slot & 3;
        srow[c] = r;
        scol[c] = (sl ^ ((r >> 1) & 3)) << 3;
        sdst[c] = (c * 256 + w * 64) * 8;
    }
    const int arow = wm * 64 + (lane & 15);
    const int brow = wn * 64 + (lane & 15);
    const int kq = lane >> 4;

    for (int kt = 0; kt < KK; kt += 32) {
        __syncthreads();
        #pragma unroll
        for (int c = 0; c < 2; ++c) {
            gload16(Xh + (size_t)(m0 + srow[c]) * KK + kt + scol[c], &As[sdst[c]]);
            gload16(Wh + (size_t)(n0 + srow[c]) * KK + kt + scol[c], &Bs[sdst[c]]);
        }
        __syncthreads();

        half8 af[4], bf[4];
        #pragma unroll
        for (int mi = 0; mi < 4; ++mi) {
            int r = arow + mi * 16;
            af[mi] = *(const half8*)&As[r * 32 + ((kq ^ ((r >> 1) & 3)) << 3)];
        }
        #pragma unroll
        for (int ni = 0; ni < 4; ++ni) {
            int r = brow + ni * 16;
            bf[ni] = *(const half8*)&Bs[r * 32 + ((kq ^ ((r >> 1) & 3)) << 3)];
        }
        #pragma unroll
        for (int mi = 0; mi < 4; ++mi)
            #pragma unroll
            for (int ni = 0; ni < 4; ++ni)
                acc[mi][ni] = __builtin_amdgcn_mfma_f32_16x16x32_f16(af[mi], bf[ni], acc[mi][ni], 0, 0, 0);
    }

    #pragma unroll
    for (int ni = 0; ni < 4; ++ni) {
        int n = n0 + wn * 64 + ni * 16 + (lane & 15);
        float bv = bias[n];
        int h = n / 192;
        int rr = n - h * 192;
        int which = rr >> 6;          // 0=q 1=k 2=v
        int j = rr & 63;
        int jp = j >> 1;
        #pragma unroll
        for (int mi = 0; mi < 4; ++mi) {
            #pragma unroll
            for (int reg = 0; reg < 4; ++reg) {
                int m = m0 + wm * 64 + mi * 16 + (lane >> 4) * 4 + reg;
                int b_ = m / SS, s_ = m - b_ * SS;
                float v = acc[mi][ni][reg] + bv;
                float p = __shfl_xor(v, 1);              // pair partner (before divergence)
                size_t bh = (size_t)b_ * HH + h;
                if (which == 2) {
                    vt[(bh * HD + j) * SP + s_] = (_Float16)v;
                } else {
                    float2 cs = *(const float2*)&rope[(s_ * 32 + jp) * 2];
                    float o = (j & 1) ? fmaf(p, cs.y, v * cs.x) : fmaf(v, cs.x, -p * cs.y);
                    if (which == 0)
                        qo[(bh * SS + s_) * HD + j] = (_Float16)(o * 0.125f);
                    else
                        ko[(bh * SS + s_) * HD + j] = (_Float16)o;
                }
            }
        }
    }
}

// ---------------- Attention: MFMA fp16, one block per (b,h) ----------------
// K_lds XOR-swizzled [SP][64]; VT_lds [64][SP]; per-wave 32-row Q-tiles, online softmax.
__global__ __launch_bounds__(256) void attn_mfma_kernel(
    const _Float16* __restrict__ q, const _Float16* __restrict__ k,
    const _Float16* __restrict__ vt, float* __restrict__ out)
{
    __shared__ _Float16 Klds[SP * 64];
    __shared__ _Float16 VTlds[64 * SP];
    __shared__ _Float16 Plds[4][32 * 32];

    const int bh = blockIdx.x;
    const int b_ = bh >> 4, h = bh & 15;
    const int t = threadIdx.x;
    const int w = t >> 6, lane = t & 63;
    const int l15 = lane & 15, l4 = lane >> 4;

    const _Float16* kbase = k + (size_t)bh * SS * HD;
    const _Float16* vtbase = vt + (size_t)bh * HD * SP;
    const _Float16* qbase = q + (size_t)bh * SS * HD;

    // stage K with per-row XOR chunk swizzle (8 x 16B chunks per 64-elem row)
    for (int c = t; c < SP * 8; c += 256) {
        int row = c >> 3, g = c & 7;
        int rowc = row < SS ? row : (SS - 1);          // clamp; masked anyway
        float4 val = *(const float4*)(kbase + rowc * HD + g * 8);
        *(float4*)&Klds[row * 64 + ((g ^ (row & 7)) * 8)] = val;
    }
    // stage VT rows straight (26 x 16B chunks per SP-elem row)
    for (int c = t; c < 64 * 26; c += 256) {
        int row = c / 26, g = c - row * 26;
        *(float4*)&VTlds[row * SP + g * 8] = *(const float4*)(vtbase + row * SP + g * 8);
    }
    __syncthreads();

    const int qts[2] = { w, 6 - w };
    const int nqt = (w == 3) ? 1 : 2;

    for (int qi = 0; qi < nqt; ++qi) {
        const int qt = qts[qi];
        const int q0 = qt * 32;

        half8 qf[2][2];
        #pragma unroll
        for (int mt = 0; mt < 2; ++mt)
            #pragma unroll
            for (int ks = 0; ks < 2; ++ks)
                qf[mt][ks] = *(const half8*)(qbase + (size_t)(q0 + mt * 16 + l15) * HD + ks * 32 + l4 * 8);

        float mrow[2][4], lrow[2][4];
        f32x4 oacc[2][4];
        #pragma unroll
        for (int mt = 0; mt < 2; ++mt) {
            #pragma unroll
            for (int r = 0; r < 4; ++r) { mrow[mt][r] = -1e30f; lrow[mt][r] = 0.f; }
            #pragma unroll
            for (int nt = 0; nt < 4; ++nt) oacc[mt][nt] = (f32x4)0.f;
        }

        for (int kt = 0; kt <= qt; ++kt) {
            const int k0 = kt * 32;
            half8 kf[2][2];
            #pragma unroll
            for (int nt = 0; nt < 2; ++nt)
                #pragma unroll
                for (int ks = 0; ks < 2; ++ks) {
                    int row = k0 + nt * 16 + l15;
                    int g = l4 + ks * 4;
                    kf[nt][ks] = *(const half8*)&Klds[row * 64 + ((g ^ (row & 7)) * 8)];
                }
            f32x4 s[2][2];
            #pragma unroll
            for (int mt = 0; mt < 2; ++mt)
                #pragma unroll
                for (int nt = 0; nt < 2; ++nt) {
                    f32x4 a = (f32x4)0.f;
                    a = __builtin_amdgcn_mfma_f32_16x16x32_f16(qf[mt][0], kf[nt][0], a, 0, 0, 0);
                    a = __builtin_amdgcn_mfma_f32_16x16x32_f16(qf[mt][1], kf[nt][1], a, 0, 0, 0);
                    s[mt][nt] = a;
                }
            if (kt == qt) {   // diagonal (and tail) masking
                #pragma unroll
                for (int mt = 0; mt < 2; ++mt)
                    #pragma unroll
                    for (int nt = 0; nt < 2; ++nt)
                        #pragma unroll
                        for (int r = 0; r < 4; ++r) {
                            int qq = q0 + mt * 16 + l4 * 4 + r;
                            int kk2 = k0 + nt * 16 + l15;
                            if (kk2 > qq || kk2 >= SS) s[mt][nt][r] = -1e30f;
                        }
            }
            // online softmax update (rows live in (mt, reg); k across 2 nt + 16 lanes)
            #pragma unroll
            for (int mt = 0; mt < 2; ++mt) {
                #pragma unroll
                for (int r = 0; r < 4; ++r) {
                    float tm = fmaxf(s[mt][0][r], s[mt][1][r]);
                    #pragma unroll
                    for (int off = 8; off > 0; off >>= 1)
                        tm = fmaxf(tm, __shfl_xor(tm, off));
                    float mo = mrow[mt][r];
                    float mn = fmaxf(mo, tm);
                    float sc = __expf(mo - mn);
                    float p0 = __expf(s[mt][0][r] - mn);
                    float p1 = __expf(s[mt][1][r] - mn);
                    s[mt][0][r] = p0; s[mt][1][r] = p1;
                    float rs = p0 + p1;
                    #pragma unroll
                    for (int off = 8; off > 0; off >>= 1)
                        rs += __shfl_xor(rs, off);
                    mrow[mt][r] = mn;
                    lrow[mt][r] = lrow[mt][r] * sc + rs;
                    #pragma unroll
                    for (int nt = 0; nt < 4; ++nt)
                        oacc[mt][nt][r] *= sc;
                }
            }
            // P -> LDS (fp16), relayout for PV A-fragments
            #pragma unroll
            for (int mt = 0; mt < 2; ++mt)
                #pragma unroll
                for (int nt = 0; nt < 2; ++nt)
                    #pragma unroll
                    for (int r = 0; r < 4; ++r)
                        Plds[w][(mt * 16 + l4 * 4 + r) * 32 + nt * 16 + l15] = (_Float16)s[mt][nt][r];
            asm volatile("s_waitcnt lgkmcnt(0)" ::: "memory");
            __builtin_amdgcn_sched_barrier(0);
            half8 pa[2], vb[4];
            #pragma unroll
            for (int mt = 0; mt < 2; ++mt)
                pa[mt] = *(const half8*)&Plds[w][(mt * 16 + l15) * 32 + l4 * 8];
            #pragma unroll
            for (int nt = 0; nt < 4; ++nt)
                vb[nt] = *(const half8*)&VTlds[(nt * 16 + l15) * SP + k0 + l4 * 8];
            #pragma unroll
            for (int mt = 0; mt < 2; ++mt)
                #pragma unroll
                for (int nt = 0; nt < 4; ++nt)
                    oacc[mt][nt] = __builtin_amdgcn_mfma_f32_16x16x32_f16(pa[mt], vb[nt], oacc[mt][nt], 0, 0, 0);
        }
        // epilogue: divide by l, store valid rows
        #pragma unroll
        for (int mt = 0; mt < 2; ++mt) {
            #pragma unroll
            for (int r = 0; r < 4; ++r) {
                int s_ = q0 + mt * 16 + l4 * 4 + r;
                if (s_ < SS) {
                    float rinv = 1.0f / lrow[mt][r];
                    #pragma unroll
                    for (int nt = 0; nt < 4; ++nt)
                        out[((size_t)b_ * SS + s_) * DD + h * HD + nt * 16 + l15] = oacc[mt][nt][r] * rinv;
                }
            }
        }
    }
}

extern "C" void kernel_launch(void* const* d_in, const int* in_sizes, int n_in,
                              void* d_out, int out_size, void* d_ws, size_t ws_size,
                              hipStream_t stream) {
    const float* x    = (const float*)d_in[0];
    // d_in[1] = mask: deterministic causal tril -> applied analytically
    const float* W    = (const float*)d_in[2];
    const float* bias = (const float*)d_in[3];
    float* out = (float*)d_out;

    char* ws = (char*)d_ws;
    float*    rope = (float*)ws;                                   // 51.2 KB
    _Float16* Xh   = (_Float16*)(ws + 65536);                      // 26.2 MB
    _Float16* Wh   = (_Float16*)(ws + 65536 + 26214400ull);        // 6.3 MB
    _Float16* Qh   = (_Float16*)(ws + 65536 + 26214400ull + 6291456ull);
    _Float16* Kh   = Qh + (size_t)BB * HH * SS * HD;
    _Float16* VTh  = Kh + (size_t)BB * HH * SS * HD;

    f32_to_f16_kernel<<<2048, 256, 0, stream>>>(x, Xh, MM * KK / 8);
    f32_to_f16_kernel<<<1024, 256, 0, stream>>>(W, Wh, N3 * KK / 8);
    rope_table_kernel<<<(SS * 32 + 255) / 256, 256, 0, stream>>>(rope);
    qkv_gemm_f16_kernel<<<dim3(N3 / 128, MM / 128), dim3(256), 0, stream>>>(Xh, Wh, bias, rope, Qh, Kh, VTh);
    attn_mfma_kernel<<<BB * HH, 256, 0, stream>>>(Qh, Kh, VTh, out);
}

// Round 11
// 356.042 us; speedup vs baseline: 3.2373x; 1.0083x over previous
//
#include <hip/hip_runtime.h>
#include <hip/hip_bf16.h>

#define BB 64
#define SS 200
#define DD 1024
#define HH 16
#define HD 64
#define N3 3072
#define MM (BB*SS)       // 12800
#define KK DD            // 1024
#define SPV 216          // padded V^T row length (word-stride 108 = 12 mod 32 -> 2-way max)

using half8 = __attribute__((ext_vector_type(8))) _Float16;
using f32x4 = __attribute__((ext_vector_type(4))) float;

__device__ __forceinline__ void gload16(const void* g, void* l) {
    __builtin_amdgcn_global_load_lds(
        (const __attribute__((address_space(1))) void*)g,
        (__attribute__((address_space(3))) void*)l, 16, 0, 0);
}

// ---------------- fp32 -> fp16 conversion ----------------
__global__ __launch_bounds__(256) void f32_to_f16_kernel(const float* __restrict__ in,
                                                         _Float16* __restrict__ out, int n8) {
    int i = blockIdx.x * 256 + threadIdx.x;
    int stride = gridDim.x * 256;
    for (; i < n8; i += stride) {
        float4 a = ((const float4*)in)[i * 2];
        float4 b = ((const float4*)in)[i * 2 + 1];
        half8 h;
        h[0] = (_Float16)a.x; h[1] = (_Float16)a.y; h[2] = (_Float16)a.z; h[3] = (_Float16)a.w;
        h[4] = (_Float16)b.x; h[5] = (_Float16)b.y; h[6] = (_Float16)b.z; h[7] = (_Float16)b.w;
        ((half8*)out)[i] = h;
    }
}

// ---------------- RoPE cos/sin table: [S][32] pairs (cos, sin) ----------------
__global__ __launch_bounds__(256) void rope_table_kernel(float* __restrict__ rope) {
    int t = blockIdx.x * 256 + threadIdx.x;
    if (t >= SS * 32) return;
    int s = t >> 5, i = t & 31;
    float inv = powf(10000.0f, -(float)(2 * i) / 64.0f);
    float ang = (float)s * inv;
    rope[t * 2 + 0] = cosf(ang);
    rope[t * 2 + 1] = sinf(ang);
}

// ---------------- QKV GEMM: fp16 MFMA 16x16x32, 128x128 tile, BK=32, 2-phase dbuf ----------------
__device__ __forceinline__ void gemm_step(const _Float16* Asb, const _Float16* Bsb,
                                          int arow, int brow, int kq,
                                          f32x4 (&acc)[4][4]) {
    half8 af[4], bf[4];
    #pragma unroll
    for (int mi = 0; mi < 4; ++mi) {
        int r = arow + mi * 16;
        af[mi] = *(const half8*)&Asb[r * 32 + ((kq ^ ((r >> 1) & 3)) << 3)];
    }
    #pragma unroll
    for (int ni = 0; ni < 4; ++ni) {
        int r = brow + ni * 16;
        bf[ni] = *(const half8*)&Bsb[r * 32 + ((kq ^ ((r >> 1) & 3)) << 3)];
    }
    __builtin_amdgcn_s_setprio(1);
    #pragma unroll
    for (int mi = 0; mi < 4; ++mi)
        #pragma unroll
        for (int ni = 0; ni < 4; ++ni)
            acc[mi][ni] = __builtin_amdgcn_mfma_f32_16x16x32_f16(af[mi], bf[ni], acc[mi][ni], 0, 0, 0);
    __builtin_amdgcn_s_setprio(0);
}

// Epilogue: +bias, RoPE(q,k), q scaled by 1/8; writes fp16 Q,K [bh][S][hd], fp16 V^T [bh][hd][SPV]
__global__ __launch_bounds__(256) void qkv_gemm_f16_kernel(
    const _Float16* __restrict__ Xh, const _Float16* __restrict__ Wh,
    const float* __restrict__ bias, const float* __restrict__ rope,
    _Float16* __restrict__ qo, _Float16* __restrict__ ko, _Float16* __restrict__ vt)
{
    __shared__ _Float16 As[2][128 * 32];
    __shared__ _Float16 Bs[2][128 * 32];

    const int t = threadIdx.x;
    const int w = t >> 6, lane = t & 63;
    const int wm = w >> 1, wn = w & 1;
    const int m0 = blockIdx.y * 128, n0 = blockIdx.x * 128;

    f32x4 acc[4][4];
    #pragma unroll
    for (int i = 0; i < 4; ++i)
        #pragma unroll
        for (int j = 0; j < 4; ++j) acc[i][j] = (f32x4)0.f;

    int srow[2], scol[2], sdst[2];
    #pragma unroll
    for (int c = 0; c < 2; ++c) {
        int slot = c * 256 + t;
        int r = slot >> 2, sl = slot & 3;
        srow[c] = r;
        scol[c] = (sl ^ ((r >> 1) & 3)) << 3;
        sdst[c] = (c * 256 + w * 64) * 8;
    }
    const int arow = wm * 64 + (lane & 15);
    const int brow = wn * 64 + (lane & 15);
    const int kq = lane >> 4;

    const _Float16* Xb = Xh + (size_t)m0 * KK;
    const _Float16* Wb = Wh + (size_t)n0 * KK;

    #pragma unroll
    for (int c = 0; c < 2; ++c) {
        gload16(Xb + (size_t)srow[c] * KK + scol[c], &As[0][sdst[c]]);
        gload16(Wb + (size_t)srow[c] * KK + scol[c], &Bs[0][sdst[c]]);
    }
    asm volatile("s_waitcnt vmcnt(0)" ::: "memory");
    __builtin_amdgcn_s_barrier();

    for (int kt = 0; kt < KK; kt += 64) {
        #pragma unroll
        for (int c = 0; c < 2; ++c) {
            gload16(Xb + (size_t)srow[c] * KK + kt + 32 + scol[c], &As[1][sdst[c]]);
            gload16(Wb + (size_t)srow[c] * KK + kt + 32 + scol[c], &Bs[1][sdst[c]]);
        }
        gemm_step(As[0], Bs[0], arow, brow, kq, acc);
        asm volatile("s_waitcnt vmcnt(0)" ::: "memory");
        __builtin_amdgcn_s_barrier();
        if (kt + 64 < KK) {
            #pragma unroll
            for (int c = 0; c < 2; ++c) {
                gload16(Xb + (size_t)srow[c] * KK + kt + 64 + scol[c], &As[0][sdst[c]]);
                gload16(Wb + (size_t)srow[c] * KK + kt + 64 + scol[c], &Bs[0][sdst[c]]);
            }
        }
        gemm_step(As[1], Bs[1], arow, brow, kq, acc);
        asm volatile("s_waitcnt vmcnt(0)" ::: "memory");
        __builtin_amdgcn_s_barrier();
    }

    #pragma unroll
    for (int ni = 0; ni < 4; ++ni) {
        int n = n0 + wn * 64 + ni * 16 + (lane & 15);
        float bv = bias[n];
        int h = n / 192;
        int rr = n - h * 192;
        int which = rr >> 6;          // 0=q 1=k 2=v
        int j = rr & 63;
        int jp = j >> 1;
        #pragma unroll
        for (int mi = 0; mi < 4; ++mi) {
            #pragma unroll
            for (int reg = 0; reg < 4; ++reg) {
                int m = m0 + wm * 64 + mi * 16 + (lane >> 4) * 4 + reg;
                int b_ = m / SS, s_ = m - b_ * SS;
                float v = acc[mi][ni][reg] + bv;
                float p = __shfl_xor(v, 1);              // pair partner (before divergence)
                size_t bh = (size_t)b_ * HH + h;
                if (which == 2) {
                    vt[(bh * HD + j) * SPV + s_] = (_Float16)v;
                } else {
                    float2 cs = *(const float2*)&rope[(s_ * 32 + jp) * 2];
                    float o = (j & 1) ? fmaf(p, cs.y, v * cs.x) : fmaf(v, cs.x, -p * cs.y);
                    if (which == 0)
                        qo[(bh * SS + s_) * HD + j] = (_Float16)(o * 0.125f);
                    else
                        ko[(bh * SS + s_) * HD + j] = (_Float16)o;
                }
            }
        }
    }
}

// ---------------- Attention: MFMA fp16, one block per (b,h), KVBLK=64 ----------------
// Klds XOR-swizzled [256][64]; VTlds [64][SPV]; Plds XOR-swizzled [4][32][64].
// Waves: w<3 -> q-tiles {w, 5-w}; w==3 -> {6}. 4 kt-iters per wave (balanced).
__global__ __launch_bounds__(256) void attn_mfma_kernel(
    const _Float16* __restrict__ q, const _Float16* __restrict__ k,
    const _Float16* __restrict__ vt, float* __restrict__ out)
{
    __shared__ _Float16 Klds[256 * 64];
    __shared__ _Float16 VTlds[64 * SPV];
    __shared__ _Float16 Plds[4][32 * 64];

    const int bh = blockIdx.x;
    const int b_ = bh >> 4, h = bh & 15;
    const int t = threadIdx.x;
    const int w = t >> 6, lane = t & 63;
    const int l15 = lane & 15, l4 = lane >> 4;

    const _Float16* kbase = k + (size_t)bh * SS * HD;
    const _Float16* vtbase = vt + (size_t)bh * HD * SPV;
    const _Float16* qbase = q + (size_t)bh * SS * HD;

    // stage K (256 rows, clamp >=SS) with per-row XOR chunk swizzle
    for (int c = t; c < 256 * 8; c += 256) {
        int row = c >> 3, g = c & 7;
        int rowc = row < SS ? row : (SS - 1);
        float4 val = *(const float4*)(kbase + rowc * HD + g * 8);
        *(float4*)&Klds[row * 64 + ((g ^ (row & 7)) * 8)] = val;
    }
    // stage VT rows straight (27 x 16B chunks per SPV-elem row)
    for (int c = t; c < 64 * 27; c += 256) {
        int row = c / 27, g = c - row * 27;
        *(float4*)&VTlds[row * SPV + g * 8] = *(const float4*)(vtbase + row * SPV + g * 8);
    }
    __syncthreads();

    const int qts[2] = { (w == 3) ? 6 : w, 5 - w };
    const int nqt = (w == 3) ? 1 : 2;

    for (int qi = 0; qi < nqt; ++qi) {
        const int qt = qts[qi];
        const int q0 = qt * 32;
        const int nkt = (q0 + 95) >> 6;     // #64-wide k-tiles for this q-tile

        half8 qf[2][2];
        #pragma unroll
        for (int mt = 0; mt < 2; ++mt)
            #pragma unroll
            for (int ks = 0; ks < 2; ++ks)
                qf[mt][ks] = *(const half8*)(qbase + (size_t)(q0 + mt * 16 + l15) * HD + ks * 32 + l4 * 8);

        float mrow[2][4], lsum[2][4];
        f32x4 oacc[2][4];
        #pragma unroll
        for (int mt = 0; mt < 2; ++mt) {
            #pragma unroll
            for (int r = 0; r < 4; ++r) { mrow[mt][r] = -1e30f; lsum[mt][r] = 0.f; }
            #pragma unroll
            for (int nt = 0; nt < 4; ++nt) oacc[mt][nt] = (f32x4)0.f;
        }

        for (int ki = 0; ki < nkt; ++ki) {
            const int k0 = ki * 64;
            const bool lastk = (ki == nkt - 1);

            // K fragments: 4 nt x 2 ks
            half8 kf[4][2];
            #pragma unroll
            for (int nt = 0; nt < 4; ++nt)
                #pragma unroll
                for (int ks = 0; ks < 2; ++ks) {
                    int row = k0 + nt * 16 + l15;
                    int g = l4 + ks * 4;
                    kf[nt][ks] = *(const half8*)&Klds[row * 64 + ((g ^ (row & 7)) * 8)];
                }
            // QK^T
            f32x4 s[2][4];
            __builtin_amdgcn_s_setprio(1);
            #pragma unroll
            for (int mt = 0; mt < 2; ++mt)
                #pragma unroll
                for (int nt = 0; nt < 4; ++nt) {
                    f32x4 a = (f32x4)0.f;
                    a = __builtin_amdgcn_mfma_f32_16x16x32_f16(qf[mt][0], kf[nt][0], a, 0, 0, 0);
                    a = __builtin_amdgcn_mfma_f32_16x16x32_f16(qf[mt][1], kf[nt][1], a, 0, 0, 0);
                    s[mt][nt] = a;
                }
            __builtin_amdgcn_s_setprio(0);

            if (lastk) {   // diagonal + tail masking (only possible on the last k-tile)
                #pragma unroll
                for (int mt = 0; mt < 2; ++mt)
                    #pragma unroll
                    for (int nt = 0; nt < 4; ++nt)
                        #pragma unroll
                        for (int r = 0; r < 4; ++r) {
                            int qq = q0 + mt * 16 + l4 * 4 + r;
                            int kk2 = k0 + nt * 16 + l15;
                            if (kk2 > qq || kk2 >= SS) s[mt][nt][r] = -1e30f;
                        }
            }

            // online softmax: max-reduce over l15; deferred-sum; defer-max THR=4
            #pragma unroll
            for (int mt = 0; mt < 2; ++mt) {
                float tmax[4];
                int ok = 1;
                #pragma unroll
                for (int r = 0; r < 4; ++r) {
                    float tm = fmaxf(fmaxf(s[mt][0][r], s[mt][1][r]),
                                     fmaxf(s[mt][2][r], s[mt][3][r]));
                    #pragma unroll
                    for (int off = 8; off > 0; off >>= 1)
                        tm = fmaxf(tm, __shfl_xor(tm, off));
                    tmax[r] = tm;
                    ok &= (tm <= mrow[mt][r] + 4.0f) ? 1 : 0;
                }
                if (__all(ok)) {
                    #pragma unroll
                    for (int r = 0; r < 4; ++r) {
                        float mo = mrow[mt][r];
                        float ps = 0.f;
                        #pragma unroll
                        for (int nt = 0; nt < 4; ++nt) {
                            float p = __expf(s[mt][nt][r] - mo);
                            s[mt][nt][r] = p;
                            ps += p;
                        }
                        lsum[mt][r] += ps;
                    }
                } else {
                    #pragma unroll
                    for (int r = 0; r < 4; ++r) {
                        float mo = mrow[mt][r];
                        float mn = fmaxf(mo, tmax[r]);
                        float sc = __expf(mo - mn);
                        mrow[mt][r] = mn;
                        float ps = 0.f;
                        #pragma unroll
                        for (int nt = 0; nt < 4; ++nt) {
                            float p = __expf(s[mt][nt][r] - mn);
                            s[mt][nt][r] = p;
                            ps += p;
                        }
                        lsum[mt][r] = lsum[mt][r] * sc + ps;
                        #pragma unroll
                        for (int nt = 0; nt < 4; ++nt)
                            oacc[mt][nt][r] *= sc;
                    }
                }
            }

            // P -> Plds (fp16) with XOR chunk swizzle: elem(row,col) at
            // row*64 + ((col>>3 ^ (row&7))*8) + (col&7)
            #pragma unroll
            for (int mt = 0; mt < 2; ++mt)
                #pragma unroll
                for (int nt = 0; nt < 4; ++nt)
                    #pragma unroll
                    for (int r = 0; r < 4; ++r) {
                        int row = mt * 16 + l4 * 4 + r;
                        int col = nt * 16 + l15;
                        Plds[w][row * 64 + (((col >> 3) ^ (row & 7)) * 8) + (col & 7)] =
                            (_Float16)s[mt][nt][r];
                    }

            // PV: A = P (q x 64 keys), B = V^T rows (d x 64 keys)
            // vb offset clamped to stay in-row: clamp only engages for fully-masked
            // key chunks (>=208, P=0), avoiding OOB reads of neighboring LDS.
            half8 pa[2][2], vb[4][2];
            #pragma unroll
            for (int mt = 0; mt < 2; ++mt)
                #pragma unroll
                for (int ksl = 0; ksl < 2; ++ksl) {
                    int row = mt * 16 + l15;
                    pa[mt][ksl] = *(const half8*)&Plds[w][row * 64 + (((ksl * 4 + l4) ^ (row & 7)) * 8)];
                }
            #pragma unroll
            for (int nt = 0; nt < 4; ++nt)
                #pragma unroll
                for (int ksl = 0; ksl < 2; ++ksl) {
                    int koff = k0 + ksl * 32 + l4 * 8;
                    koff = (koff > SPV - 8) ? (SPV - 8) : koff;
                    vb[nt][ksl] = *(const half8*)&VTlds[(nt * 16 + l15) * SPV + koff];
                }
            __builtin_amdgcn_s_setprio(1);
            #pragma unroll
            for (int mt = 0; mt < 2; ++mt)
                #pragma unroll
                for (int nt = 0; nt < 4; ++nt) {
                    oacc[mt][nt] = __builtin_amdgcn_mfma_f32_16x16x32_f16(pa[mt][0], vb[nt][0], oacc[mt][nt], 0, 0, 0);
                    oacc[mt][nt] = __builtin_amdgcn_mfma_f32_16x16x32_f16(pa[mt][1], vb[nt][1], oacc[mt][nt], 0, 0, 0);
                }
            __builtin_amdgcn_s_setprio(0);
        }

        // epilogue: final cross-lane sum of lsum, divide, store
        #pragma unroll
        for (int mt = 0; mt < 2; ++mt) {
            #pragma unroll
            for (int r = 0; r < 4; ++r) {
                float l = lsum[mt][r];
                #pragma unroll
                for (int off = 8; off > 0; off >>= 1)
                    l += __shfl_xor(l, off);
                int s_ = q0 + mt * 16 + l4 * 4 + r;
                if (s_ < SS) {
                    float rinv = 1.0f / l;
                    #pragma unroll
                    for (int nt = 0; nt < 4; ++nt)
                        out[((size_t)b_ * SS + s_) * DD + h * HD + nt * 16 + l15] = oacc[mt][nt][r] * rinv;
                }
            }
        }
    }
}

extern "C" void kernel_launch(void* const* d_in, const int* in_sizes, int n_in,
                              void* d_out, int out_size, void* d_ws, size_t ws_size,
                              hipStream_t stream) {
    const float* x    = (const float*)d_in[0];
    // d_in[1] = mask: deterministic causal tril -> applied analytically
    const float* W    = (const float*)d_in[2];
    const float* bias = (const float*)d_in[3];
    float* out = (float*)d_out;

    char* ws = (char*)d_ws;
    float*    rope = (float*)ws;                                   // 51.2 KB
    _Float16* Xh   = (_Float16*)(ws + 65536);                      // 26.2 MB
    _Float16* Wh   = (_Float16*)(ws + 65536 + 26214400ull);        // 6.3 MB
    _Float16* Qh   = (_Float16*)(ws + 65536 + 26214400ull + 6291456ull);
    _Float16* Kh   = Qh + (size_t)BB * HH * SS * HD;               // 13.1 MB each
    _Float16* VTh  = Kh + (size_t)BB * HH * SS * HD;               // 28.3 MB

    f32_to_f16_kernel<<<2048, 256, 0, stream>>>(x, Xh, MM * KK / 8);
    f32_to_f16_kernel<<<1024, 256, 0, stream>>>(W, Wh, N3 * KK / 8);
    rope_table_kernel<<<(SS * 32 + 255) / 256, 256, 0, stream>>>(rope);
    qkv_gemm_f16_kernel<<<dim3(N3 / 128, MM / 128), dim3(256), 0, stream>>>(Xh, Wh, bias, rope, Qh, Kh, VTh);
    attn_mfma_kernel<<<BB * HH, 256, 0, stream>>>(Qh, Kh, VTh, out);
}